// Round 12
// baseline (185.361 us; speedup 1.0000x reference)
//
#include <hip/hip_runtime.h>

#define TPB 64

// Fused CIoU, 1 thread/element, 1 WAVE per block (TPB=64).
// r11 baseline + three deltas:
//   1. TPB 256->64: 4096 blocks -> finer CU packing (r11 showed ~14%
//      occupancy from block-granularity skew); epilogue needs no LDS/barrier.
//   2. __launch_bounds__(64,3): VGPR cap 170 (r11's clean 128 + headroom).
//   3. t0/t1 interval chains split into two independent 4-deep halves
//      (block-local temps only) -> half the per-edge critical path.
// Codegen law (r3/r4/r6/r7/r8/r9): serial chains + block-local temps only.
// No arrays, no in-loop shuffles, no cross-block hoists.
__global__ __launch_bounds__(TPB, 3) void ciou_fused(
    const float* __restrict__ A,
    const float* __restrict__ Bq,
    float* __restrict__ out,
    double* __restrict__ acc,
    unsigned int* __restrict__ cnt,
    int nbatch, int nblocks)
{
    const int t = threadIdx.x;
    const int i0 = blockIdx.x * TPB + t;
    const bool live = (i0 < nbatch);
    const int i = live ? i0 : (nbatch - 1);

    float ax0,ax1,ax2,ax3,ax4,ax5,ax6,ax7;
    float ay0,ay1,ay2,ay3,ay4,ay5,ay6,ay7;
    float bx0,bx1,bx2,bx3,bx4,bx5,bx6,bx7;
    float by0,by1,by2,by3,by4,by5,by6,by7;
    {
        const float4* pa = (const float4*)(A + (size_t)i * 16);
        const float4* pb = (const float4*)(Bq + (size_t)i * 16);
        float4 q;
        q = pa[0]; ax0=q.x; ay0=q.y; ax1=q.z; ay1=q.w;
        q = pa[1]; ax2=q.x; ay2=q.y; ax3=q.z; ay3=q.w;
        q = pa[2]; ax4=q.x; ay4=q.y; ax5=q.z; ay5=q.w;
        q = pa[3]; ax6=q.x; ay6=q.y; ax7=q.z; ay7=q.w;
        q = pb[0]; bx0=q.x; by0=q.y; bx1=q.z; by1=q.w;
        q = pb[1]; bx2=q.x; by2=q.y; bx3=q.z; by3=q.w;
        q = pb[2]; bx4=q.x; by4=q.y; bx5=q.z; by5=q.w;
        q = pb[3]; bx6=q.x; by6=q.y; bx7=q.z; by7=q.w;
    }

    // Shoelace areas (input vertex order is CCW; sort_poly = rotation).
    float area_a = 0.5f * ((ax0*ay1-ay0*ax1) + (ax1*ay2-ay1*ax2)
                         + (ax2*ay3-ay2*ax3) + (ax3*ay4-ay3*ax4)
                         + (ax4*ay5-ay4*ax5) + (ax5*ay6-ay5*ax6)
                         + (ax6*ay7-ay6*ax7) + (ax7*ay0-ay7*ax0));
    float area_b = 0.5f * ((bx0*by1-by0*bx1) + (bx1*by2-by1*bx2)
                         + (bx2*by3-by2*bx3) + (bx3*by4-by3*bx4)
                         + (bx4*by5-by4*bx5) + (bx5*by6-by5*bx6)
                         + (bx6*by7-by6*bx7) + (bx7*by0-by7*bx0));

    // ---- Intersection: Green's theorem over clipped edges ----
    const float INFP = __builtin_inff();
    float inter2 = 0.f;

    // inside Q iff cross(E_Q, p - V_Q) >= 0; along edge: aa + t*bb >= 0.
    // T0/T1 name the half-interval accumulators (two independent chains).
#define HP(T0,T1,QX0,QY0,QX1,QY1) { \
        float ex = (QX1)-(QX0), ey = (QY1)-(QY0); \
        float aa = ex*(Py-(QY0)) - ey*(Px-(QX0)); \
        float bb = ex*Dy - ey*Dx; \
        float tc = __fdividef(-aa, bb); \
        T0 = fmaxf(T0, (bb > 0.f) ? tc : -INFP); \
        T1 = fminf(T1, (bb < 0.f) ? tc :  INFP); }

#define HPB HP(t0a,t1a,bx0,by0,bx1,by1) HP(t0b,t1b,bx1,by1,bx2,by2) \
            HP(t0a,t1a,bx2,by2,bx3,by3) HP(t0b,t1b,bx3,by3,bx4,by4) \
            HP(t0a,t1a,bx4,by4,bx5,by5) HP(t0b,t1b,bx5,by5,bx6,by6) \
            HP(t0a,t1a,bx6,by6,bx7,by7) HP(t0b,t1b,bx7,by7,bx0,by0)
#define HPA HP(t0a,t1a,ax0,ay0,ax1,ay1) HP(t0b,t1b,ax1,ay1,ax2,ay2) \
            HP(t0a,t1a,ax2,ay2,ax3,ay3) HP(t0b,t1b,ax3,ay3,ax4,ay4) \
            HP(t0a,t1a,ax4,ay4,ax5,ay5) HP(t0b,t1b,ax5,ay5,ax6,ay6) \
            HP(t0a,t1a,ax6,ay6,ax7,ay7) HP(t0b,t1b,ax7,ay7,ax0,ay0)

    // cross(P(t0),P(t1)) = (t1-t0)*cross(P,D) ; t0>=0, t1<=1 by construction
#define EDGE(PX,PY,QX,QY,HPS) { \
        const float Px = (PX), Py = (PY); \
        const float Dx = (QX) - Px, Dy = (QY) - Py; \
        float t0a = 0.f, t1a = 1.f, t0b = 0.f, t1b = 1.f; \
        HPS \
        float dt = fminf(t1a, t1b) - fmaxf(t0a, t0b); \
        float cpd = Px*Dy - Py*Dx; \
        inter2 += (dt > 0.f) ? dt*cpd : 0.f; }

    EDGE(ax0,ay0,ax1,ay1,HPB) EDGE(ax1,ay1,ax2,ay2,HPB)
    EDGE(ax2,ay2,ax3,ay3,HPB) EDGE(ax3,ay3,ax4,ay4,HPB)
    EDGE(ax4,ay4,ax5,ay5,HPB) EDGE(ax5,ay5,ax6,ay6,HPB)
    EDGE(ax6,ay6,ax7,ay7,HPB) EDGE(ax7,ay7,ax0,ay0,HPB)
    EDGE(bx0,by0,bx1,by1,HPA) EDGE(bx1,by1,bx2,by2,HPA)
    EDGE(bx2,by2,bx3,by3,HPA) EDGE(bx3,by3,bx4,by4,HPA)
    EDGE(bx4,by4,bx5,by5,HPA) EDGE(bx5,by5,bx6,by6,HPA)
    EDGE(bx6,by6,bx7,by7,HPA) EDGE(bx7,by7,bx0,by0,HPA)

    float inter = fmaxf(0.5f * inter2, 0.f);
    float uni = area_a + area_b - inter;
    float iou = __fdividef(inter, uni);

    // ---- Hull start: serial min by (y,x) over all 16 ----
    float stx = ax0, sty = ay0;
#define UPD(PX,PY) { \
        bool bs = ((PY) < sty) || (((PY) == sty) && ((PX) < stx)); \
        stx = bs ? (PX) : stx; sty = bs ? (PY) : sty; }
    UPD(ax1,ay1) UPD(ax2,ay2) UPD(ax3,ay3) UPD(ax4,ay4)
    UPD(ax5,ay5) UPD(ax6,ay6) UPD(ax7,ay7)
    UPD(bx0,by0) UPD(bx1,by1) UPD(bx2,by2) UPD(bx3,by3)
    UPD(bx4,by4) UPD(bx5,by5) UPD(bx6,by6) UPD(bx7,by7)

    // ---- Jarvis march, candidate seeded with negated incoming direction ----
    // (r9/r10-validated: every true candidate beats -din via cross<0; the
    // self-point gives cr==0, never taken; nx/ny select exact original
    // coords so the done-equality matches the reference's termination.)
    float cxv = stx, cyv = sty, accH = 0.f;
    float pdx = 1.f, pdy = 0.f;          // reference's initial heading (1,0)
    bool done = false;
    for (int it = 0; it < 16; ++it) {
        float cdx = -pdx, cdy = -pdy;
        float nx = cxv, ny = cyv;
#define SCAN(PX,PY) { \
            float vx = (PX) - cxv, vy = (PY) - cyv; \
            float cr = cdx*vy - cdy*vx; \
            bool take = cr < 0.f; \
            nx = take ? (PX) : nx;  ny = take ? (PY) : ny; \
            cdx = take ? vx : cdx;  cdy = take ? vy : cdy; }
        SCAN(ax0,ay0) SCAN(ax1,ay1) SCAN(ax2,ay2) SCAN(ax3,ay3)
        SCAN(ax4,ay4) SCAN(ax5,ay5) SCAN(ax6,ay6) SCAN(ax7,ay7)
        SCAN(bx0,by0) SCAN(bx1,by1) SCAN(bx2,by2) SCAN(bx3,by3)
        SCAN(bx4,by4) SCAN(bx5,by5) SCAN(bx6,by6) SCAN(bx7,by7)
        accH += done ? 0.f : (cxv*ny - cyv*nx);
        done = done || (nx == stx && ny == sty);
        pdx = cdx; pdy = cdy;
        cxv = nx; cyv = ny;
        if (__all(done)) break;
    }
    float ch = 0.5f * accH;

    float val = iou - __fdividef(ch - uni, ch);
    float v = live ? val : 0.f;

    // ---- reduction: single wave -> shuffle -> one double atomic ----
    #pragma unroll
    for (int off = 32; off > 0; off >>= 1) v += __shfl_down(v, off);
    if (t == 0) {
        atomicAdd(acc, (double)v);
        __threadfence();
        unsigned int old = atomicAdd(cnt, 1u);
        if (old == (unsigned int)(nblocks - 1)) {
            double total = atomicAdd(acc, 0.0);   // read after all adds visible
            out[0] = (float)(total / (double)nbatch);
        }
    }
}

extern "C" void kernel_launch(void* const* d_in, const int* in_sizes, int n_in,
                              void* d_out, int out_size, void* d_ws, size_t ws_size,
                              hipStream_t stream) {
    const float* a = (const float*)d_in[0];
    const float* b = (const float*)d_in[1];
    float* out = (float*)d_out;
    int nbatch = in_sizes[0] / 16;
    int nblocks = (nbatch + TPB - 1) / TPB;
    double* acc = (double*)d_ws;                          // [0,8): double sum
    unsigned int* cnt = (unsigned int*)((char*)d_ws + 8); // [8,12): counter
    hipMemsetAsync(d_ws, 0, 16, stream);
    ciou_fused<<<nblocks, TPB, 0, stream>>>(a, b, out, acc, cnt, nbatch, nblocks);
}

// Round 13
// 112.052 us; speedup vs baseline: 1.6542x; 1.6542x over previous
//
#include <hip/hip_runtime.h>

#define TPB 256

// Fused CIoU, 1 thread/element — r11 baseline (proven 55.6us, clean 128-VGPR
// allocation) + two strictly LOCAL deltas:
//   1. t0/t1 interval chains split into two independent 4-deep halves
//      (block-local temps, merged once per edge).
//   2. Branchless HP: h = bb*1e38 ; t0 = fmax(t0, fmin(tc,h)) ;
//      t1 = fmin(t1, fmax(tc,h)).  bb>0 -> h huge positive -> picks tc for
//      t0, +big sentinel for t1; bb<0 symmetric; bb==0 (parallel edges) is
//      measure-zero, dropped since r10 with absmax 0.0. IEEE min/max absorb
//      the NaN arm. Removes 2 v_cmp + 2 v_cndmask (and vcc serialization)
//      per HP x 128.
// Codegen law (r3/r4/r6/r7/r8/r9/r12): serial chains + block-local temps,
// TPB=256, shuffles only in the epilogue. No arrays, no in-loop shuffles,
// no cross-block hoists, no 64-thread blocks.
__global__ __launch_bounds__(TPB, 2) void ciou_fused(
    const float* __restrict__ A,
    const float* __restrict__ Bq,
    float* __restrict__ out,
    double* __restrict__ acc,
    unsigned int* __restrict__ cnt,
    int nbatch, int nblocks)
{
    const int t = threadIdx.x;
    const int i0 = blockIdx.x * TPB + t;
    const bool live = (i0 < nbatch);
    const int i = live ? i0 : (nbatch - 1);

    float ax0,ax1,ax2,ax3,ax4,ax5,ax6,ax7;
    float ay0,ay1,ay2,ay3,ay4,ay5,ay6,ay7;
    float bx0,bx1,bx2,bx3,bx4,bx5,bx6,bx7;
    float by0,by1,by2,by3,by4,by5,by6,by7;
    {
        const float4* pa = (const float4*)(A + (size_t)i * 16);
        const float4* pb = (const float4*)(Bq + (size_t)i * 16);
        float4 q;
        q = pa[0]; ax0=q.x; ay0=q.y; ax1=q.z; ay1=q.w;
        q = pa[1]; ax2=q.x; ay2=q.y; ax3=q.z; ay3=q.w;
        q = pa[2]; ax4=q.x; ay4=q.y; ax5=q.z; ay5=q.w;
        q = pa[3]; ax6=q.x; ay6=q.y; ax7=q.z; ay7=q.w;
        q = pb[0]; bx0=q.x; by0=q.y; bx1=q.z; by1=q.w;
        q = pb[1]; bx2=q.x; by2=q.y; bx3=q.z; by3=q.w;
        q = pb[2]; bx4=q.x; by4=q.y; bx5=q.z; by5=q.w;
        q = pb[3]; bx6=q.x; by6=q.y; bx7=q.z; by7=q.w;
    }

    // Shoelace areas (input vertex order is CCW; sort_poly = rotation).
    float area_a = 0.5f * ((ax0*ay1-ay0*ax1) + (ax1*ay2-ay1*ax2)
                         + (ax2*ay3-ay2*ax3) + (ax3*ay4-ay3*ax4)
                         + (ax4*ay5-ay4*ax5) + (ax5*ay6-ay5*ax6)
                         + (ax6*ay7-ay6*ax7) + (ax7*ay0-ay7*ax0));
    float area_b = 0.5f * ((bx0*by1-by0*bx1) + (bx1*by2-by1*bx2)
                         + (bx2*by3-by2*bx3) + (bx3*by4-by3*bx4)
                         + (bx4*by5-by4*bx5) + (bx5*by6-by5*bx6)
                         + (bx6*by7-by6*bx7) + (bx7*by0-by7*bx0));

    // ---- Intersection: Green's theorem over clipped edges ----
    float inter2 = 0.f;

    // inside Q iff cross(E_Q, p - V_Q) >= 0; along edge: aa + t*bb >= 0.
#define HP(T0,T1,QX0,QY0,QX1,QY1) { \
        float ex = (QX1)-(QX0), ey = (QY1)-(QY0); \
        float aa = ex*(Py-(QY0)) - ey*(Px-(QX0)); \
        float bb = ex*Dy - ey*Dx; \
        float tc = __fdividef(-aa, bb); \
        float h = bb * 1e38f; \
        T0 = fmaxf(T0, fminf(tc, h)); \
        T1 = fminf(T1, fmaxf(tc, h)); }

#define HPB HP(t0a,t1a,bx0,by0,bx1,by1) HP(t0b,t1b,bx1,by1,bx2,by2) \
            HP(t0a,t1a,bx2,by2,bx3,by3) HP(t0b,t1b,bx3,by3,bx4,by4) \
            HP(t0a,t1a,bx4,by4,bx5,by5) HP(t0b,t1b,bx5,by5,bx6,by6) \
            HP(t0a,t1a,bx6,by6,bx7,by7) HP(t0b,t1b,bx7,by7,bx0,by0)
#define HPA HP(t0a,t1a,ax0,ay0,ax1,ay1) HP(t0b,t1b,ax1,ay1,ax2,ay2) \
            HP(t0a,t1a,ax2,ay2,ax3,ay3) HP(t0b,t1b,ax3,ay3,ax4,ay4) \
            HP(t0a,t1a,ax4,ay4,ax5,ay5) HP(t0b,t1b,ax5,ay5,ax6,ay6) \
            HP(t0a,t1a,ax6,ay6,ax7,ay7) HP(t0b,t1b,ax7,ay7,ax0,ay0)

    // cross(P(t0),P(t1)) = (t1-t0)*cross(P,D) ; t0>=0, t1<=1 by construction
#define EDGE(PX,PY,QX,QY,HPS) { \
        const float Px = (PX), Py = (PY); \
        const float Dx = (QX) - Px, Dy = (QY) - Py; \
        float t0a = 0.f, t1a = 1.f, t0b = 0.f, t1b = 1.f; \
        HPS \
        float dt = fminf(t1a, t1b) - fmaxf(t0a, t0b); \
        float cpd = Px*Dy - Py*Dx; \
        inter2 += (dt > 0.f) ? dt*cpd : 0.f; }

    EDGE(ax0,ay0,ax1,ay1,HPB) EDGE(ax1,ay1,ax2,ay2,HPB)
    EDGE(ax2,ay2,ax3,ay3,HPB) EDGE(ax3,ay3,ax4,ay4,HPB)
    EDGE(ax4,ay4,ax5,ay5,HPB) EDGE(ax5,ay5,ax6,ay6,HPB)
    EDGE(ax6,ay6,ax7,ay7,HPB) EDGE(ax7,ay7,ax0,ay0,HPB)
    EDGE(bx0,by0,bx1,by1,HPA) EDGE(bx1,by1,bx2,by2,HPA)
    EDGE(bx2,by2,bx3,by3,HPA) EDGE(bx3,by3,bx4,by4,HPA)
    EDGE(bx4,by4,bx5,by5,HPA) EDGE(bx5,by5,bx6,by6,HPA)
    EDGE(bx6,by6,bx7,by7,HPA) EDGE(bx7,by7,bx0,by0,HPA)

    float inter = fmaxf(0.5f * inter2, 0.f);
    float uni = area_a + area_b - inter;
    float iou = __fdividef(inter, uni);

    // ---- Hull start: serial min by (y,x) over all 16 ----
    float stx = ax0, sty = ay0;
#define UPD(PX,PY) { \
        bool bs = ((PY) < sty) || (((PY) == sty) && ((PX) < stx)); \
        stx = bs ? (PX) : stx; sty = bs ? (PY) : sty; }
    UPD(ax1,ay1) UPD(ax2,ay2) UPD(ax3,ay3) UPD(ax4,ay4)
    UPD(ax5,ay5) UPD(ax6,ay6) UPD(ax7,ay7)
    UPD(bx0,by0) UPD(bx1,by1) UPD(bx2,by2) UPD(bx3,by3)
    UPD(bx4,by4) UPD(bx5,by5) UPD(bx6,by6) UPD(bx7,by7)

    // ---- Jarvis march, candidate seeded with negated incoming direction ----
    // (r9/r10-validated: every true candidate beats -din via cross<0; the
    // self-point gives cr==0, never taken; nx/ny select exact original
    // coords so the done-equality matches the reference's termination.)
    float cxv = stx, cyv = sty, accH = 0.f;
    float pdx = 1.f, pdy = 0.f;          // reference's initial heading (1,0)
    bool done = false;
    for (int it = 0; it < 16; ++it) {
        float cdx = -pdx, cdy = -pdy;
        float nx = cxv, ny = cyv;
#define SCAN(PX,PY) { \
            float vx = (PX) - cxv, vy = (PY) - cyv; \
            float cr = cdx*vy - cdy*vx; \
            bool take = cr < 0.f; \
            nx = take ? (PX) : nx;  ny = take ? (PY) : ny; \
            cdx = take ? vx : cdx;  cdy = take ? vy : cdy; }
        SCAN(ax0,ay0) SCAN(ax1,ay1) SCAN(ax2,ay2) SCAN(ax3,ay3)
        SCAN(ax4,ay4) SCAN(ax5,ay5) SCAN(ax6,ay6) SCAN(ax7,ay7)
        SCAN(bx0,by0) SCAN(bx1,by1) SCAN(bx2,by2) SCAN(bx3,by3)
        SCAN(bx4,by4) SCAN(bx5,by5) SCAN(bx6,by6) SCAN(bx7,by7)
        accH += done ? 0.f : (cxv*ny - cyv*nx);
        done = done || (nx == stx && ny == sty);
        pdx = cdx; pdy = cdy;
        cxv = nx; cyv = ny;
        if (__all(done)) break;
    }
    float ch = 0.5f * accH;

    float val = iou - __fdividef(ch - uni, ch);
    float v = live ? val : 0.f;

    // ---- reduction: wave shuffle -> LDS(16B) -> global double atomic ----
    #pragma unroll
    for (int off = 32; off > 0; off >>= 1) v += __shfl_down(v, off);
    __shared__ float wsum[4];
    int lane = t & 63, wid = t >> 6;
    if (lane == 0) wsum[wid] = v;
    __syncthreads();
    if (t == 0) {
        double bsum = (double)wsum[0] + (double)wsum[1]
                    + (double)wsum[2] + (double)wsum[3];
        atomicAdd(acc, bsum);
        __threadfence();
        unsigned int old = atomicAdd(cnt, 1u);
        if (old == (unsigned int)(nblocks - 1)) {
            double total = atomicAdd(acc, 0.0);   // read after all adds visible
            out[0] = (float)(total / (double)nbatch);
        }
    }
}

extern "C" void kernel_launch(void* const* d_in, const int* in_sizes, int n_in,
                              void* d_out, int out_size, void* d_ws, size_t ws_size,
                              hipStream_t stream) {
    const float* a = (const float*)d_in[0];
    const float* b = (const float*)d_in[1];
    float* out = (float*)d_out;
    int nbatch = in_sizes[0] / 16;
    int nblocks = (nbatch + TPB - 1) / TPB;
    double* acc = (double*)d_ws;                          // [0,8): double sum
    unsigned int* cnt = (unsigned int*)((char*)d_ws + 8); // [8,12): counter
    hipMemsetAsync(d_ws, 0, 16, stream);
    ciou_fused<<<nblocks, TPB, 0, stream>>>(a, b, out, acc, cnt, nbatch, nblocks);
}